// Round 1
// 253.861 us; speedup vs baseline: 1.0036x; 1.0036x over previous
//
#include <hip/hip_runtime.h>

// out[b][i][j] = (j == indices[i]) ? grad[b][i] : 0
// grad (8,4096) f32, indices (4096,) int32, out (8,4096,2048) f32 = 256 MiB.
// Pure write-stream; floor = 268 MB / 6.5 TB/s ~= 41 us (+ the harness's
// ~164 us 1 GiB re-poison fill that is included in dur_us).
//
// R5: same structure as R4 (1024 blocks x 512 threads = 32 waves/CU in one
// dispatch round, 32 rows/block, prefetched (idx, grad) scalars), but the
// per-row element insert is now BRANCHLESS with STATIC vector indices:
//   c = idx[r] - 4*t;  v.{x,y,z,w} = (c == {0,1,2,3}) ? g[r] : 0
// R4 used `if (idx>>2 == t) v[idx&3] = g` -- a variable-index insertelement
// under a divergent branch, which AMDGPU lowers via scratch / waterfall
// (guide rule #20). That put a ~200-cycle scratch round-trip on the critical
// path of every one of the 32 dwordx4 stores -> 2.9 TB/s instead of 6.5.
// Four v_cmp+v_cndmask per store is pure VALU and fully hidden under the
// store stream.

#define ROWS_PER_B 4096
#define NEWDIM     2048
#define F4_PER_ROW (NEWDIM / 4)   // 512
#define RPI        8              // rows per inner iteration
#define ITERS      4              // iterations per block -> 32 rows/block

typedef float f32x4 __attribute__((ext_vector_type(4)));

__global__ __launch_bounds__(512)
void ReduceMaxGrad_53833120088407_kernel(const float* __restrict__ grad,
                                         const int*  __restrict__ indices,
                                         float*      __restrict__ out) {
    const int t    = threadIdx.x;                  // 0..511 -> one float4 per row
    const int t4   = t << 2;                       // first element this thread owns
    const int row0 = blockIdx.x * (RPI * ITERS);   // 32 contiguous rows per block

    int   idx[RPI];
    float g[RPI];
#pragma unroll
    for (int r = 0; r < RPI; ++r) {                // prefetch group 0
        idx[r] = indices[(row0 + r) & (ROWS_PER_B - 1)];
        g[r]   = grad[row0 + r];
    }

    f32x4* o = (f32x4*)out + (size_t)row0 * F4_PER_ROW + t;

#pragma unroll
    for (int it = 0; it < ITERS; ++it) {
        int   nidx[RPI];
        float ng[RPI];
        if (it + 1 < ITERS) {                      // prefetch group it+1
            const int nrow0 = row0 + (it + 1) * RPI;
#pragma unroll
            for (int r = 0; r < RPI; ++r) {
                nidx[r] = indices[(nrow0 + r) & (ROWS_PER_B - 1)];
                ng[r]   = grad[nrow0 + r];
            }
        }
#pragma unroll
        for (int r = 0; r < RPI; ++r) {            // 8 back-to-back dwordx4 stores
            const int c = idx[r] - t4;             // in [0,3] iff this thread owns it
            f32x4 v;
            v.x = (c == 0) ? g[r] : 0.0f;          // static indices: pure
            v.y = (c == 1) ? g[r] : 0.0f;          // v_cmp + v_cndmask, no
            v.z = (c == 2) ? g[r] : 0.0f;          // scratch, no divergent
            v.w = (c == 3) ? g[r] : 0.0f;          // branch, no waterfall
            o[(size_t)(it * RPI + r) * F4_PER_ROW] = v;
        }
        if (it + 1 < ITERS) {
#pragma unroll
            for (int r = 0; r < RPI; ++r) { idx[r] = nidx[r]; g[r] = ng[r]; }
        }
    }
}

extern "C" void kernel_launch(void* const* d_in, const int* in_sizes, int n_in,
                              void* d_out, int out_size, void* d_ws, size_t ws_size,
                              hipStream_t stream) {
    const float* grad    = (const float*)d_in[0];   // (8, 4096) f32
    const int*   indices = (const int*)d_in[1];     // (4096,) int32
    float*       out     = (float*)d_out;           // (8, 4096, 2048) f32

    const int n_rows   = in_sizes[0];               // 32768
    const int n_blocks = n_rows / (RPI * ITERS);    // 1024
    ReduceMaxGrad_53833120088407_kernel<<<dim3(n_blocks), dim3(512), 0, stream>>>(
        grad, indices, out);
}